// Round 1
// baseline (479.523 us; speedup 1.0000x reference)
//
#include <hip/hip_runtime.h>
#include <hip/hip_bf16.h>

// Problem constants (from reference setup_inputs): B=4, L=2048, D=1024, vocab<32, N_GRAM=3
#define LSEQ 2048
#define DDIM 1024

// ---------------- Kernel 1: pack trailing 3-gram into a 15-bit key ----------------
__global__ void keys_kernel(const int* __restrict__ ids, int* __restrict__ keys, int total) {
    int idx = blockIdx.x * 256 + threadIdx.x;
    if (idx >= total) return;
    int i = idx & (LSEQ - 1);
    int k = 0;
    if (i >= 2) k = (ids[idx - 2] << 10) | (ids[idx - 1] << 5) | ids[idx];
    keys[idx] = k;  // i<2 -> padded zero 3-gram -> key 0 (matches reference pad semantics)
}

// ---------------- Kernel 2: pooled[b,i,:] = mean_{j<i, key[j]==key[i]} H[b,j,:] ----
// One block per output row (b,i); 256 threads each own 4 columns (float4).
// Deterministic match collection via shared bitmap (no order-dependent fp sums).
__global__ __launch_bounds__(256) void pooled_kernel(const float4* __restrict__ H4,
                                                     const int* __restrict__ keys,
                                                     float4* __restrict__ P4) {
    int row = blockIdx.x;            // b*L + i
    int i = row & (LSEQ - 1);
    int base = row - i;              // b*L
    int tid = threadIdx.x;
    int key_i = keys[row];

    __shared__ unsigned bm[8];
    float4 acc = make_float4(0.f, 0.f, 0.f, 0.f);
    int count = 0;

    for (int j0 = 0; j0 < i; j0 += 256) {
        if (tid < 8) bm[tid] = 0u;
        __syncthreads();
        int j = j0 + tid;
        if (j < i && keys[base + j] == key_i)
            atomicOr(&bm[tid >> 5], 1u << (tid & 31));
        __syncthreads();
        #pragma unroll
        for (int w = 0; w < 8; ++w) {
            unsigned m = bm[w];
            while (m) {
                int bit = __ffs(m) - 1;
                m &= m - 1;
                int j2 = j0 + w * 32 + bit;
                count++;
                float4 h = H4[(size_t)(base + j2) * (DDIM / 4) + tid];
                acc.x += h.x; acc.y += h.y; acc.z += h.z; acc.w += h.w;
            }
        }
        __syncthreads();
    }
    float s = 1.0f / (float)(count > 0 ? count : 1);
    acc.x *= s; acc.y *= s; acc.z *= s; acc.w *= s;
    P4[(size_t)row * (DDIM / 4) + tid] = acc;
}

// ---------------- Kernel 3: out = H@W1 + P@W2 + (b1+b2) ---------------------------
// fp32 vector GEMM. 64x64 block tile, 16x16 threads x (4x4 micro-tile), BK=16.
#define BM 64
#define BN 64
#define BK 16
__global__ __launch_bounds__(256) void gemm_fused(const float* __restrict__ H,
                                                  const float* __restrict__ P,
                                                  const float* __restrict__ W1,
                                                  const float* __restrict__ b1,
                                                  const float* __restrict__ W2,
                                                  const float* __restrict__ b2,
                                                  float* __restrict__ out,
                                                  int M, int N, int K) {
    __shared__ float As[BK][BM + 1];  // A transposed, +1 pad to break bank conflicts
    __shared__ float Bs[BK][BN];

    int tid = threadIdx.x;
    int row0 = blockIdx.x * BM;
    int col0 = blockIdx.y * BN;
    int tx = tid & 15, ty = tid >> 4;

    float acc[4][4] = {};

    int ar = tid >> 2;             // A-load row within tile (0..63)
    int ac = (tid & 3) * 4;        // A-load k-offset (0,4,8,12)
    int bk = tid >> 4;             // B-load k row (0..15)
    int bn2 = (tid & 15) * 4;      // B-load col offset (0..60)

    for (int path = 0; path < 2; ++path) {
        const float* A = path ? P : H;
        const float* W = path ? W2 : W1;
        for (int k0 = 0; k0 < K; k0 += BK) {
            float4 av = *(const float4*)&A[(size_t)(row0 + ar) * K + k0 + ac];
            float4 wv = *(const float4*)&W[(size_t)(k0 + bk) * N + col0 + bn2];
            As[ac + 0][ar] = av.x;
            As[ac + 1][ar] = av.y;
            As[ac + 2][ar] = av.z;
            As[ac + 3][ar] = av.w;
            *(float4*)&Bs[bk][bn2] = wv;
            __syncthreads();
            #pragma unroll
            for (int kk = 0; kk < BK; ++kk) {
                float a[4], bb[4];
                #pragma unroll
                for (int q = 0; q < 4; ++q) a[q] = As[kk][ty * 4 + q];
                #pragma unroll
                for (int r = 0; r < 4; ++r) bb[r] = Bs[kk][tx * 4 + r];
                #pragma unroll
                for (int q = 0; q < 4; ++q)
                    #pragma unroll
                    for (int r = 0; r < 4; ++r)
                        acc[q][r] += a[q] * bb[r];
            }
            __syncthreads();
        }
    }

    #pragma unroll
    for (int q = 0; q < 4; ++q) {
        int rr = row0 + ty * 4 + q;
        #pragma unroll
        for (int r = 0; r < 4; ++r) {
            int cc = col0 + tx * 4 + r;
            out[(size_t)rr * N + cc] = acc[q][r] + b1[cc] + b2[cc];
        }
    }
}

extern "C" void kernel_launch(void* const* d_in, const int* in_sizes, int n_in,
                              void* d_out, int out_size, void* d_ws, size_t ws_size,
                              hipStream_t stream) {
    const float* H  = (const float*)d_in[0];
    const int*   ids = (const int*)d_in[1];   // jax default: int64 request -> int32 actual
    const float* W1 = (const float*)d_in[2];
    const float* b1 = (const float*)d_in[3];
    const float* W2 = (const float*)d_in[4];
    const float* b2 = (const float*)d_in[5];
    float* out = (float*)d_out;

    const int BL = in_sizes[1];      // B*L = 8192
    const int D  = in_sizes[3];      // 1024

    int* keys = (int*)d_ws;                                  // 32 KB
    float* pooled = (float*)((char*)d_ws + 65536);           // 32 MB

    keys_kernel<<<(BL + 255) / 256, 256, 0, stream>>>(ids, keys, BL);
    pooled_kernel<<<BL, 256, 0, stream>>>((const float4*)H, keys, (float4*)pooled);
    gemm_fused<<<dim3(BL / BM, D / BN), 256, 0, stream>>>(H, pooled, W1, b1, W2, b2, out,
                                                          BL, D, D);
}

// Round 2
// 98.369 us; speedup vs baseline: 4.8747x; 4.8747x over previous
//
#include <hip/hip_runtime.h>
#include <hip/hip_bf16.h>
#include <stdint.h>

// Problem constants: B=4, L=2048, D=1024, vocab<32, N_GRAM=3
#define LSEQ 2048
#define DDIM 1024

typedef __attribute__((ext_vector_type(8))) short bf16x8;
typedef __attribute__((ext_vector_type(4))) float f32x4;

__device__ __forceinline__ ushort f2bf(float x) {
    uint32_t u = __builtin_bit_cast(uint32_t, x);
    u += 0x7fffu + ((u >> 16) & 1u);   // round-to-nearest-even (inputs are finite/normal)
    return (ushort)(u >> 16);
}

__device__ __forceinline__ void stage16(const void* g, void* lds) {
    __builtin_amdgcn_global_load_lds((const __attribute__((address_space(1))) void*)g,
                                     (__attribute__((address_space(3))) void*)lds, 16, 0, 0);
}

// ---------------- Kernel 1: pack trailing 3-gram into a 15-bit key ----------------
__global__ void keys_kernel(const int* __restrict__ ids, int* __restrict__ keys, int total) {
    int idx = blockIdx.x * 256 + threadIdx.x;
    if (idx >= total) return;
    int i = idx & (LSEQ - 1);
    int k = 0;
    if (i >= 2) k = (ids[idx - 2] << 10) | (ids[idx - 1] << 5) | ids[idx];
    keys[idx] = k;  // i<2 -> padded zero 3-gram -> key 0 (matches reference pad semantics)
}

// ---------------- Kernel 2: pooled[b,i,:] = mean_{j<i, key[j]==key[i]} H[b,j,:] ----
// One block per output row; deterministic LDS-bitmap match collection; bf16 output.
__global__ __launch_bounds__(256) void pooled_kernel(const float4* __restrict__ H4,
                                                     const int* __restrict__ keys,
                                                     ushort* __restrict__ Pb) {
    int row = blockIdx.x;            // b*L + i
    int i = row & (LSEQ - 1);
    int base = row - i;              // b*L
    int tid = threadIdx.x;
    int key_i = keys[row];

    __shared__ unsigned bm[8];
    float4 acc = make_float4(0.f, 0.f, 0.f, 0.f);
    int count = 0;

    for (int j0 = 0; j0 < i; j0 += 256) {
        if (tid < 8) bm[tid] = 0u;
        __syncthreads();
        int j = j0 + tid;
        if (j < i && keys[base + j] == key_i)
            atomicOr(&bm[tid >> 5], 1u << (tid & 31));
        __syncthreads();
        #pragma unroll
        for (int w = 0; w < 8; ++w) {
            unsigned m = bm[w];
            while (m) {
                int bit = __ffs(m) - 1;
                m &= m - 1;
                int j2 = j0 + w * 32 + bit;
                count++;
                float4 h = H4[(size_t)(base + j2) * (DDIM / 4) + tid];
                acc.x += h.x; acc.y += h.y; acc.z += h.z; acc.w += h.w;
            }
        }
        __syncthreads();
    }
    float s = 1.0f / (float)(count > 0 ? count : 1);
    ushort4 o;
    o.x = f2bf(acc.x * s); o.y = f2bf(acc.y * s);
    o.z = f2bf(acc.z * s); o.w = f2bf(acc.w * s);
    *(ushort4*)&Pb[(size_t)row * DDIM + tid * 4] = o;
}

// ---------------- Kernel 3: W[K][N] fp32 -> Wt[N][K] bf16 (both W1, W2) -----------
__global__ __launch_bounds__(256) void transpose_w(const float* __restrict__ W1,
                                                   const float* __restrict__ W2,
                                                   ushort* __restrict__ W1t,
                                                   ushort* __restrict__ W2t) {
    const float* W = blockIdx.z ? W2 : W1;
    ushort* Wt = blockIdx.z ? W2t : W1t;
    __shared__ ushort t[64][65];
    int k0 = blockIdx.x * 64, n0 = blockIdx.y * 64;
    int tid = threadIdx.x;
    #pragma unroll
    for (int it = 0; it < 16; ++it) {
        int idx = it * 256 + tid;
        int r = idx >> 6, c = idx & 63;
        t[c][r] = f2bf(W[(size_t)(k0 + r) * DDIM + n0 + c]);
    }
    __syncthreads();
    #pragma unroll
    for (int it = 0; it < 16; ++it) {
        int idx = it * 256 + tid;
        int r = idx >> 6, c = idx & 63;
        Wt[(size_t)(n0 + r) * DDIM + k0 + c] = t[r][c];
    }
}

// ---------------- Kernel 4: out = H@W1 + P@W2 + (b1+b2), bf16 MFMA ---------------
// 128x128 tile, 4 waves (2x2), each wave 4x4 of 16x16x32 fragments, BK=32.
// LDS tiles As/Bs are [128 rows][32 k] bf16 (linear, global_load_lds-compatible).
// k-mapping on both A and B fragments: k = (lane>>4)*8 + j  (consistent-kappa).
__global__ __launch_bounds__(256) void gemm_bf16(
    const float* __restrict__ H,      // [8192][1024] fp32 (converted in-flight)
    const ushort* __restrict__ Pb,    // [8192][1024] bf16
    const ushort* __restrict__ W1t,   // [1024 n][1024 k] bf16
    const ushort* __restrict__ W2t,
    const float* __restrict__ b1,
    const float* __restrict__ b2,
    float* __restrict__ out)          // [8192][1024] fp32
{
    __shared__ __align__(16) short As[128 * 32];   // 8 KB
    __shared__ __align__(16) short Bs[128 * 32];   // 8 KB

    const int tid = threadIdx.x;
    const int lane = tid & 63;
    const int wid = tid >> 6;
    const int wr = wid >> 1, wc = wid & 1;
    const int lr = lane & 15, hi = lane >> 4;

    const int row0 = blockIdx.x * 128;
    const int col0 = blockIdx.y * 128;

    f32x4 acc[4][4];
    #pragma unroll
    for (int m = 0; m < 4; ++m)
        #pragma unroll
        for (int n = 0; n < 4; ++n)
            acc[m][n] = (f32x4){0.f, 0.f, 0.f, 0.f};

    // staging geometry for bf16 tiles: 8KB = 2 issues x (4 waves x 64 lanes x 16B)
    const int o_lin = wid * 1024 + lane * 16;   // byte offset within one 4KB issue
    const int srow  = o_lin >> 6;               // tile row (64B = one row's 32 bf16)
    const int sbyte = o_lin & 63;               // byte within row
    // A path-0 (H fp32 -> bf16 reg-convert): thread covers As elements [tid*16, +16)
    const int arow  = tid >> 1;
    const int akoff = (tid & 1) * 16;
    const float* Hrow = H + (size_t)(row0 + arow) * DDIM + akoff;
    short* As_dst = As + tid * 16;

    const short* Aread = As + (wr * 64 + lr) * 32 + hi * 8;
    const short* Bread = Bs + (wc * 64 + lr) * 32 + hi * 8;

    // ---------------- path 0: H @ W1 ----------------
    for (int k0 = 0; k0 < DDIM; k0 += 32) {
        const char* bg0 = (const char*)W1t + ((size_t)(col0 + srow) * DDIM + k0) * 2 + sbyte;
        const char* bg1 = (const char*)W1t + ((size_t)(col0 + srow + 64) * DDIM + k0) * 2 + sbyte;
        stage16(bg0, (char*)Bs + wid * 1024);
        stage16(bg1, (char*)Bs + 4096 + wid * 1024);

        float4 v0 = *(const float4*)(Hrow + k0);
        float4 v1 = *(const float4*)(Hrow + k0 + 4);
        float4 v2 = *(const float4*)(Hrow + k0 + 8);
        float4 v3 = *(const float4*)(Hrow + k0 + 12);
        union { ushort u[16]; int4 v[2]; } t;
        t.u[0] = f2bf(v0.x); t.u[1] = f2bf(v0.y); t.u[2]  = f2bf(v0.z); t.u[3]  = f2bf(v0.w);
        t.u[4] = f2bf(v1.x); t.u[5] = f2bf(v1.y); t.u[6]  = f2bf(v1.z); t.u[7]  = f2bf(v1.w);
        t.u[8] = f2bf(v2.x); t.u[9] = f2bf(v2.y); t.u[10] = f2bf(v2.z); t.u[11] = f2bf(v2.w);
        t.u[12] = f2bf(v3.x); t.u[13] = f2bf(v3.y); t.u[14] = f2bf(v3.z); t.u[15] = f2bf(v3.w);
        *(int4*)As_dst = t.v[0];
        *(int4*)(As_dst + 8) = t.v[1];

        __syncthreads();   // compiler drains vmcnt+lgkmcnt before s_barrier
        bf16x8 af[4], bfr[4];
        #pragma unroll
        for (int m = 0; m < 4; ++m) af[m]  = *(const bf16x8*)(Aread + m * 16 * 32);
        #pragma unroll
        for (int n = 0; n < 4; ++n) bfr[n] = *(const bf16x8*)(Bread + n * 16 * 32);
        #pragma unroll
        for (int m = 0; m < 4; ++m)
            #pragma unroll
            for (int n = 0; n < 4; ++n)
                acc[m][n] = __builtin_amdgcn_mfma_f32_16x16x32_bf16(af[m], bfr[n], acc[m][n], 0, 0, 0);
        __syncthreads();
    }

    // ---------------- path 1: P @ W2 ----------------
    for (int k0 = 0; k0 < DDIM; k0 += 32) {
        const char* ag0 = (const char*)Pb + ((size_t)(row0 + srow) * DDIM + k0) * 2 + sbyte;
        const char* ag1 = (const char*)Pb + ((size_t)(row0 + srow + 64) * DDIM + k0) * 2 + sbyte;
        stage16(ag0, (char*)As + wid * 1024);
        stage16(ag1, (char*)As + 4096 + wid * 1024);
        const char* bg0 = (const char*)W2t + ((size_t)(col0 + srow) * DDIM + k0) * 2 + sbyte;
        const char* bg1 = (const char*)W2t + ((size_t)(col0 + srow + 64) * DDIM + k0) * 2 + sbyte;
        stage16(bg0, (char*)Bs + wid * 1024);
        stage16(bg1, (char*)Bs + 4096 + wid * 1024);

        __syncthreads();
        bf16x8 af[4], bfr[4];
        #pragma unroll
        for (int m = 0; m < 4; ++m) af[m]  = *(const bf16x8*)(Aread + m * 16 * 32);
        #pragma unroll
        for (int n = 0; n < 4; ++n) bfr[n] = *(const bf16x8*)(Bread + n * 16 * 32);
        #pragma unroll
        for (int m = 0; m < 4; ++m)
            #pragma unroll
            for (int n = 0; n < 4; ++n)
                acc[m][n] = __builtin_amdgcn_mfma_f32_16x16x32_bf16(af[m], bfr[n], acc[m][n], 0, 0, 0);
        __syncthreads();
    }

    // epilogue: C/D layout col=lane&15, row=(lane>>4)*4+reg (m89-verified)
    #pragma unroll
    for (int m = 0; m < 4; ++m) {
        #pragma unroll
        for (int n = 0; n < 4; ++n) {
            int c = col0 + wc * 64 + n * 16 + lr;
            float bias = b1[c] + b2[c];
            #pragma unroll
            for (int q = 0; q < 4; ++q) {
                int r = row0 + wr * 64 + m * 16 + hi * 4 + q;
                out[(size_t)r * DDIM + c] = acc[m][n][q] + bias;
            }
        }
    }
}

extern "C" void kernel_launch(void* const* d_in, const int* in_sizes, int n_in,
                              void* d_out, int out_size, void* d_ws, size_t ws_size,
                              hipStream_t stream) {
    const float* H  = (const float*)d_in[0];
    const int*   ids = (const int*)d_in[1];
    const float* W1 = (const float*)d_in[2];
    const float* b1 = (const float*)d_in[3];
    const float* W2 = (const float*)d_in[4];
    const float* b2 = (const float*)d_in[5];
    float* out = (float*)d_out;

    const int BL = in_sizes[1];      // B*L = 8192

    char* ws = (char*)d_ws;
    int* keys   = (int*)ws;                                   // 64 KB reserved
    ushort* Pb  = (ushort*)(ws + (64 << 10));                 // 16 MB bf16 pooled
    ushort* W1t = (ushort*)(ws + (64 << 10) + (16 << 20));    // 2 MB
    ushort* W2t = (ushort*)(ws + (64 << 10) + (18 << 20));    // 2 MB
    // total ~20.06 MB < proven-available 33.6 MB

    keys_kernel<<<(BL + 255) / 256, 256, 0, stream>>>(ids, keys, BL);
    pooled_kernel<<<BL, 256, 0, stream>>>((const float4*)H, keys, Pb);
    transpose_w<<<dim3(16, 16, 2), 256, 0, stream>>>(W1, W2, W1t, W2t);
    gemm_bf16<<<dim3(BL / 128, DDIM / 128), 256, 0, stream>>>(H, Pb, W1t, W2t, b1, b2, out);
}